// Round 3
// baseline (265.887 us; speedup 1.0000x reference)
//
#include <hip/hip_runtime.h>
#include <hip/hip_bf16.h>

#define D 64
#define KCODES 1024
// Approx-path error budget (distance units):
//   bf16 hi/lo split residual (proven <=0.025 in prior session at MARGIN=0.25)
// + MFMA accumulation rounding at magnitude ~2048-5700 (C-init biased): <=0.10 worst
// + key quantization 2 x 63*ULP(<2^13) = 2 x 0.031
// => 2*eps <= ~0.38 < MARGIN. Flags ~1% of rows, handled exactly by rescore.
#define MARGIN 0.6f
#define OFFSET 2048.0f   // makes approx distance strictly positive => uint-sortable bits

typedef __attribute__((ext_vector_type(8))) short bf16x8;
typedef __attribute__((ext_vector_type(4))) float f32x4;

__device__ __forceinline__ unsigned short f2bf(float f) {
    union { __hip_bfloat16 h; unsigned short s; } cv;
    cv.h = __float2bfloat16(f);
    return cv.s;
}
__device__ __forceinline__ float bf2f(unsigned short v) {
    union { unsigned short s; __hip_bfloat16 h; } cv;
    cv.s = v;
    return __bfloat162float(cv.h);
}

// k0: e2[k] = ||e_k||^2 (exact, same summation as proven round-2 arithmetic),
// e2b[k] = e2[k] + OFFSET (approx path only), bf16 hi/lo split, zero counter.
__global__ __launch_bounds__(256) void prep_kernel(
    const float* __restrict__ emb, float* __restrict__ e2, float* __restrict__ e2b,
    unsigned short* __restrict__ ehi, unsigned short* __restrict__ elo,
    unsigned int* __restrict__ counter) {
    int t = blockIdx.x * 256 + threadIdx.x;
    if (t == 0) *counter = 0u;
    if (t < KCODES) {
        const float4* ep = (const float4*)(emb + (size_t)t * D);
        float s0 = 0.f, s1 = 0.f, s2 = 0.f, s3 = 0.f;
#pragma unroll
        for (int i = 0; i < 16; ++i) {
            float4 v = ep[i];
            s0 = fmaf(v.x, v.x, s0);
            s1 = fmaf(v.y, v.y, s1);
            s2 = fmaf(v.z, v.z, s2);
            s3 = fmaf(v.w, v.w, s3);
        }
        float s = (s0 + s1) + (s2 + s3);
        e2[t] = s;          // exact, used by rescore (unchanged arithmetic)
        e2b[t] = s + OFFSET; // biased, approx path / MFMA C-init
    }
    float v = emb[t];
    unsigned short h = f2bf(v);
    ehi[t] = h;
    elo[t] = f2bf(v - bf2f(h));
}

// k1: MFMA distance argmin.
// Block = 4 waves x 32 rows = 128 rows; grid 1024 => 4 blocks/CU = 4 waves/SIMD.
// A (-2x, hi/lo split; -2x exact in bf16) held in VGPRs. B (code tiles) double-
// buffered in LDS, reg-staged (global->reg at phase top, swizzled ds_write after
// compute). LDS swizzle: 16B slot p of row r holds logical slot p^(r&7) to break
// the 128B-stride bank conflict (rule #21: swizzle on write AND read).
// Distance d = e2b - 2 x.e comes straight out of the MFMA (C-init = e2b bcast),
// d in (~1900,~5700) > 0 => bits are uint-sortable. key = (bits & ~63) | tile.
// Top-2 per stream: m1 = min_u32(m1,key); m2 = v_med3_u32(m1_old,m2,key).
__global__ __launch_bounds__(256, 4) void vq_mfma_kernel(
    const float* __restrict__ x, const float* __restrict__ emb,
    const float* __restrict__ e2b, const unsigned short* __restrict__ ehi,
    const unsigned short* __restrict__ elo, float* __restrict__ out_q,
    float* __restrict__ out_idx, float* __restrict__ out_loss,
    unsigned int* __restrict__ counter, int* __restrict__ flaglist, int flag_cap) {
    __shared__ float4 lds4[2][256];   // 2 buffers x (hi 2KB | lo 2KB)
    __shared__ int s_bi[128];
    char* ldsc = (char*)&lds4[0][0];
    const int tid = threadIdx.x;
    const int lane = tid & 63;
    const int wave = __builtin_amdgcn_readfirstlane(tid >> 6);
    const int quad = lane >> 4;
    const int l15 = lane & 15;
    const int rowBase = blockIdx.x * 128 + wave * 32;

    // A fragments: 2 rowsets x 16 rows, pre-scaled by -2, bf16 hi/lo.
    bf16x8 ah[2][2], al[2][2];
#pragma unroll
    for (int rs = 0; rs < 2; ++rs) {
        const float* xr = x + (size_t)(rowBase + rs * 16 + l15) * D;
#pragma unroll
        for (int c = 0; c < 2; ++c) {
            const float4* p = (const float4*)(xr + c * 32 + quad * 8);
            float4 f0 = p[0], f1 = p[1];
            float f[8] = {f0.x, f0.y, f0.z, f0.w, f1.x, f1.y, f1.z, f1.w};
            bf16x8 h, l;
#pragma unroll
            for (int j = 0; j < 8; ++j) {
                float v = -2.0f * f[j];             // exact scale
                unsigned short hu = f2bf(v);
                h[j] = (short)hu;
                l[j] = (short)f2bf(v - bf2f(hu));   // exact (Sterbenz)
            }
            ah[rs][c] = h;
            al[rs][c] = l;
        }
    }

    // Staging addresses. Tile = 16 codes x 64 dims x 2B = 2KB (hi) + 2KB (lo).
    // Waves 0,1 stage hi halves; waves 2,3 stage lo halves. Linear global read
    // (lane*16B), swizzled LDS write.
    const int r3 = lane >> 3;            // row within 8-row half
    const int sl = lane & 7;             // 16B slot within row
    const int halfsel = wave & 1;
    const unsigned short* sbase = (wave < 2) ? ehi : elo;
    const unsigned short* gsrc0 = sbase + halfsel * 512 + lane * 8;  // + t*1024/tile
    const int wrow = halfsel * 8 + r3;
    char* wdst = ldsc + ((wave < 2) ? 0 : 2048) + wrow * 128 + ((sl ^ r3) << 4);

    // ds_read addresses (swizzled): logical slot q (c=0), q+4 (c=1) of row l15.
    const int s7 = l15 & 7;
    const int rdA = l15 * 128 + ((quad ^ s7) << 4);
    const int rdB = l15 * 128 + (((quad + 4) ^ s7) << 4);

    unsigned int m1[2][4], m2[2][4];
#pragma unroll
    for (int rs = 0; rs < 2; ++rs)
#pragma unroll
        for (int r = 0; r < 4; ++r) { m1[rs][r] = 0xFFFFFFFFu; m2[rs][r] = 0xFFFFFFFFu; }

    auto compute = [&](int t, float e2v, bf16x8 bh0, bf16x8 bh1, bf16x8 bl0, bf16x8 bl1) {
        f32x4 cvec = {e2v, e2v, e2v, e2v};   // C-init: all 4 rows, col=code=l15
        unsigned tt = (unsigned)t;
#pragma unroll
        for (int rs = 0; rs < 2; ++rs) {
            f32x4 acc = cvec;
            // Per K-chunk: hi*hi + lo*hi + hi*lo (lo*lo below threshold, omitted).
            acc = __builtin_amdgcn_mfma_f32_16x16x32_bf16(ah[rs][0], bh0, acc, 0, 0, 0);
            acc = __builtin_amdgcn_mfma_f32_16x16x32_bf16(al[rs][0], bh0, acc, 0, 0, 0);
            acc = __builtin_amdgcn_mfma_f32_16x16x32_bf16(ah[rs][0], bl0, acc, 0, 0, 0);
            acc = __builtin_amdgcn_mfma_f32_16x16x32_bf16(ah[rs][1], bh1, acc, 0, 0, 0);
            acc = __builtin_amdgcn_mfma_f32_16x16x32_bf16(al[rs][1], bh1, acc, 0, 0, 0);
            acc = __builtin_amdgcn_mfma_f32_16x16x32_bf16(ah[rs][1], bl1, acc, 0, 0, 0);
#pragma unroll
            for (int r = 0; r < 4; ++r) {
                unsigned k = (__float_as_uint(acc[r]) & 0xFFFFFFC0u) | tt;
                unsigned nm2;
                asm("v_med3_u32 %0, %1, %2, %3"
                    : "=v"(nm2)
                    : "v"(m1[rs][r]), "v"(m2[rs][r]), "v"(k));
                m2[rs][r] = nm2;                       // exact new 2nd-min
                m1[rs][r] = (k < m1[rs][r]) ? k : m1[rs][r];
            }
        }
    };

    float e2cur = e2b[l15];   // tile 0
    {   // prologue: stage tile 0 -> buf0
        float4 stg = *(const float4*)gsrc0;
        *(float4*)wdst = stg;
    }
    __syncthreads();

#pragma unroll 1
    for (int i = 0; i < 32; ++i) {
        const int tB = 2 * i + 1;
        // ---- tile 2i from buf0; issue loads for tile 2i+1 (buf1)
        float4 stgB = *(const float4*)(gsrc0 + (size_t)tB * 1024);
        float e2nA = e2b[tB * 16 + l15];
        {
            bf16x8 bh0 = *(const bf16x8*)(ldsc + rdA);
            bf16x8 bh1 = *(const bf16x8*)(ldsc + rdB);
            bf16x8 bl0 = *(const bf16x8*)(ldsc + 2048 + rdA);
            bf16x8 bl1 = *(const bf16x8*)(ldsc + 2048 + rdB);
            compute(2 * i, e2cur, bh0, bh1, bl0, bl1);
        }
        *(float4*)(wdst + 4096) = stgB;   // buf1 <- tile 2i+1 (vmcnt wait lands here)
        __syncthreads();
        // ---- tile 2i+1 from buf1; issue loads for tile 2i+2 (buf0).
        // At i=31 this stages "tile 64" = garbage from adjacent ws arrays
        // (valid memory, never read) - avoids a branch.
        float4 stgA2 = *(const float4*)(gsrc0 + (size_t)(tB + 1) * 1024);
        float e2nB = e2b[(tB + 1) * 16 + l15];
        {
            bf16x8 bh0 = *(const bf16x8*)(ldsc + 4096 + rdA);
            bf16x8 bh1 = *(const bf16x8*)(ldsc + 4096 + rdB);
            bf16x8 bl0 = *(const bf16x8*)(ldsc + 6144 + rdA);
            bf16x8 bl1 = *(const bf16x8*)(ldsc + 6144 + rdB);
            compute(tB, e2nA, bh0, bh1, bl0, bl1);
        }
        *(float4*)wdst = stgA2;           // buf0 <- tile 2i+2
        __syncthreads();
        e2cur = e2nB;
    }

    // Cross-lane merge over the 16 code-lanes; recover winner lane via ballot.
    // Near-ties (incl. all key-level ties) satisfy m2-m1 < MARGIN => rescored
    // exactly, so tie-break here need not match the reference.
#pragma unroll
    for (int rs = 0; rs < 2; ++rs)
#pragma unroll
        for (int r = 0; r < 4; ++r) {
            unsigned v1 = m1[rs][r], v2 = m2[rs][r];
            const unsigned my1 = v1;
#pragma unroll
            for (int mask = 1; mask < 16; mask <<= 1) {
                unsigned o1 = __shfl_xor(v1, mask);
                unsigned o2 = __shfl_xor(v2, mask);
                unsigned hi = v1 > o1 ? v1 : o1;
                unsigned lo2 = v2 < o2 ? v2 : o2;
                v2 = lo2 < hi ? lo2 : hi;   // union 2nd-min
                v1 = v1 < o1 ? v1 : o1;
            }
            unsigned long long bal = __ballot(my1 == v1);
            int winl = __ffsll((bal >> (quad * 16)) & 0xFFFFull) - 1;
            int code = (int)(v1 & 63u) * 16 + winl;
            if (l15 == 0) {
                int lrow = wave * 32 + rs * 16 + quad * 4 + r;
                s_bi[lrow] = code;
                float f1 = __uint_as_float(v1 & 0xFFFFFFC0u);
                float f2 = __uint_as_float(v2 & 0xFFFFFFC0u);
                if (f2 - f1 < MARGIN) {
                    unsigned slot = atomicAdd(counter, 1u);
                    if (slot < (unsigned)flag_cap) flaglist[slot] = blockIdx.x * 128 + lrow;
                }
            }
        }
    __syncthreads();

    // Fused epilogue: arithmetic kept verbatim from the proven version.
    if (tid < 128) {
        const int row = blockIdx.x * 128 + tid;
        const int bi = s_bi[tid];
        const float4* qp = (const float4*)(emb + (size_t)bi * D);
        const float4* xp = (const float4*)(x + (size_t)row * D);
        float4* oq = (float4*)(out_q + (size_t)row * D);
        float l0 = 0.f, l1 = 0.f, l2 = 0.f, l3 = 0.f;
#pragma unroll
        for (int i = 0; i < 16; ++i) {
            float4 q = qp[i];
            float4 xv = xp[i];
            float a0 = q.x - xv.x, a1 = q.y - xv.y, a2 = q.z - xv.z, a3 = q.w - xv.w;
            l0 = fmaf(a0, a0, l0);
            l1 = fmaf(a1, a1, l1);
            l2 = fmaf(a2, a2, l2);
            l3 = fmaf(a3, a3, l3);
            float4 o;
            o.x = xv.x + a0;
            o.y = xv.y + a1;
            o.z = xv.z + a2;
            o.w = xv.w + a3;
            oq[i] = o;
        }
        float s = (l0 + l1) + (l2 + l3);
        out_idx[row] = (float)bi;
        out_loss[row] = s + 0.25f * s;
    }
}

// k2: exact fp32 rescore of flagged rows, 8 rows per block-batch so the 256KB
// codebook is swept once per 8 rows (8x less L2 traffic than row-at-a-time).
// Per-(row,code) arithmetic is bit-identical to the proven round-2 formula.
__global__ __launch_bounds__(256) void rescore_kernel(
    const float* __restrict__ x, const float* __restrict__ emb,
    const float* __restrict__ e2, float* __restrict__ out_q,
    float* __restrict__ out_idx, float* __restrict__ out_loss,
    const unsigned int* __restrict__ counter, const int* __restrict__ flaglist,
    int flag_cap) {
    __shared__ float s_x[8][64];
    __shared__ int s_rows[8];
    __shared__ float s_wd[8][4];
    __shared__ int s_wi[8][4];
    __shared__ float s_a[4][64];
    unsigned int n = *counter;
    if (n > (unsigned)flag_cap) n = (unsigned)flag_cap;
    const int tid = threadIdx.x;
    const int lane = tid & 63;
    const int wv = tid >> 6;
    for (unsigned int b = blockIdx.x; b * 8u < n; b += gridDim.x) {
        const unsigned base = b * 8u;
        unsigned nbu = n - base;
        if (nbu > 8u) nbu = 8u;
        const int nb = (int)nbu;
        if (tid < 8) s_rows[tid] = flaglist[base + (tid < nb ? tid : 0)];
        __syncthreads();
        if (tid < 128) {
            int r = tid >> 4, q4 = tid & 15;
            ((float4*)&s_x[r][0])[q4] = ((const float4*)(x + (size_t)s_rows[r] * D))[q4];
        }
        __syncthreads();

        float bd_[8];
        int bi_[8];
#pragma unroll
        for (int r = 0; r < 8; ++r) { bd_[r] = 3.4e38f; bi_[r] = 0; }
        for (int kk = 0; kk < 4; ++kk) {
            const int k = tid + kk * 256;   // ascending per thread
            const float* ek = emb + (size_t)k * D;
            float d0[8], d1[8], d2[8], d3[8];
#pragma unroll
            for (int r = 0; r < 8; ++r) { d0[r] = 0.f; d1[r] = 0.f; d2[r] = 0.f; d3[r] = 0.f; }
#pragma unroll
            for (int i = 0; i < 16; ++i) {
                float4 ev = ((const float4*)ek)[i];
#pragma unroll
                for (int r = 0; r < 8; ++r) {
                    float4 xv = ((const float4*)&s_x[r][0])[i];   // LDS broadcast
                    d0[r] = fmaf(xv.x, ev.x, d0[r]);
                    d1[r] = fmaf(xv.y, ev.y, d1[r]);
                    d2[r] = fmaf(xv.z, ev.z, d2[r]);
                    d3[r] = fmaf(xv.w, ev.w, d3[r]);
                }
            }
            float e2k = e2[k];
#pragma unroll
            for (int r = 0; r < 8; ++r) {
                float dist = fmaf(-2.0f, (d0[r] + d1[r]) + (d2[r] + d3[r]), e2k);
                if (dist < bd_[r]) { bd_[r] = dist; bi_[r] = k; }
            }
        }
        // reduce: wave shuffle then cross-wave, lexicographic (dist, index)
#pragma unroll
        for (int r = 0; r < 8; ++r) {
            float v = bd_[r];
            int ix = bi_[r];
#pragma unroll
            for (int mask = 1; mask < 64; mask <<= 1) {
                float ov = __shfl_xor(v, mask);
                int oi = __shfl_xor(ix, mask);
                bool tk = (ov < v) || (ov == v && oi < ix);
                v = tk ? ov : v;
                ix = tk ? oi : ix;
            }
            if (lane == 0) { s_wd[r][wv] = v; s_wi[r][wv] = ix; }
        }
        __syncthreads();
        if (tid < 8) {
            float v = s_wd[tid][0];
            int ix = s_wi[tid][0];
#pragma unroll
            for (int w = 1; w < 4; ++w) {
                float ov = s_wd[tid][w];
                int oi = s_wi[tid][w];
                bool tk = (ov < v) || (ov == v && oi < ix);
                v = tk ? ov : v;
                ix = tk ? oi : ix;
            }
            s_wi[tid][0] = ix;
        }
        __syncthreads();
        // epilogue: 2 passes x 4 rows; original per-element + summation order.
#pragma unroll
        for (int pass = 0; pass < 2; ++pass) {
            const int rloc = pass * 4 + wv;
            const int row = s_rows[rloc];
            const int fbi = s_wi[rloc][0];
            const float xe = s_x[rloc][lane];
            const float a = emb[(size_t)fbi * D + lane] - xe;
            if (rloc < nb) out_q[(size_t)row * D + lane] = xe + a;
            s_a[wv][lane] = a * a;
            __syncthreads();
            if (lane == 0 && rloc < nb) {
                float l0 = 0.f, l1 = 0.f, l2 = 0.f, l3 = 0.f;
                for (int i2 = 0; i2 < 16; ++i2) {
                    l0 += s_a[wv][4 * i2 + 0];
                    l1 += s_a[wv][4 * i2 + 1];
                    l2 += s_a[wv][4 * i2 + 2];
                    l3 += s_a[wv][4 * i2 + 3];
                }
                float s = (l0 + l1) + (l2 + l3);
                out_loss[row] = s + 0.25f * s;
                out_idx[row] = (float)fbi;
            }
            __syncthreads();
        }
    }
}

extern "C" void kernel_launch(void* const* d_in, const int* in_sizes, int n_in,
                              void* d_out, int out_size, void* d_ws, size_t ws_size,
                              hipStream_t stream) {
    const float* x = (const float*)d_in[0];     // [B,T,D] fp32
    const float* emb = (const float*)d_in[1];   // [K,D] fp32
    const int nrows = in_sizes[0] / D;          // 131072

    float* out_q = (float*)d_out;
    float* out_idx = out_q + (size_t)nrows * D;
    float* out_loss = out_idx + nrows;

    // ws: e2 4KB | e2b 4KB | ehi 128KB | elo 128KB | counter 64B | flaglist
    char* ws = (char*)d_ws;
    float* e2 = (float*)ws;
    float* e2b = (float*)(ws + 4096);
    unsigned short* ehi = (unsigned short*)(ws + 8192);
    unsigned short* elo = (unsigned short*)(ws + 8192 + 131072);
    unsigned int* counter = (unsigned int*)(ws + 8192 + 262144);
    int* flaglist = (int*)(ws + 8192 + 262144 + 64);
    long long avail = (long long)ws_size - (8192 + 262144 + 64);
    int flag_cap = (int)(avail / 4);
    if (flag_cap > 16384) flag_cap = 16384;
    if (flag_cap < 1024) flag_cap = 1024;

    prep_kernel<<<(KCODES * D) / 256, 256, 0, stream>>>(emb, e2, e2b, ehi, elo, counter);
    vq_mfma_kernel<<<nrows / 128, 256, 0, stream>>>(x, emb, e2b, ehi, elo, out_q,
                                                    out_idx, out_loss, counter,
                                                    flaglist, flag_cap);
    rescore_kernel<<<1024, 256, 0, stream>>>(x, emb, e2, out_q, out_idx, out_loss,
                                             counter, flaglist, flag_cap);
}